// Round 11
// baseline (74.846 us; speedup 1.0000x reference)
//
#include <hip/hip_runtime.h>
#include <math.h>

// ---- problem constants (fixed by reference setup) ----
constexpr int Bc    = 4;
constexpr int Nc    = 1024;
constexpr int SEQc  = 512;
constexpr int FOURc = 257;              // rfft output length
constexpr int NROWS = Bc * Nc;          // 4096 (b,n) rows
constexpr int NSMALL = 1024;            // nodes touched by real edges
constexpr int F1c   = 30;               // H1*C1
constexpr int TT    = 256;              // folded t length
constexpr int CAP   = 128;              // max in-degree bucket capacity
constexpr float NEG_SLOPE = 0.2f;

#define DEVFN static __device__ __forceinline__

// ------- K_pre: parallel bucket scatter (CSR-lite), 32 blocks -------
__global__ __launch_bounds__(256) void k_pre(const int* __restrict__ ei, int E,
                                             int* __restrict__ cnt,
                                             int* __restrict__ srcs2) {
  const int base = blockIdx.x * 256 + threadIdx.x;
  const int tot  = E + NSMALL;
  for (int e = base; e < tot; e += 32 * 256) {
    int src, dst;
    if (e < E) { src = ei[e]; dst = ei[E + e]; }
    else       { src = dst = e - E; }     // self loops
    int pos = atomicAdd(&cnt[dst], 1);
    if (pos < CAP) srcs2[dst * CAP + pos] = src;
  }
}

// self-loop-only node value: v = elu(xf@W1 + b1) @ W2 + b2
DEVFN float node_v(float xo, float xp,
                   const float* w1s, const float* b1s, const float* w2s, float b2v) {
  float s = 0.f;
#pragma unroll
  for (int jj = 0; jj < F1c; ++jj) {
    float h = fmaf(xo, w1s[jj], fmaf(xp, w1s[F1c + jj], b1s[jj]));
    float e = h > 0.f ? h : (__expf(h) - 1.f);
    s = fmaf(e, w2s[jj], s);
  }
  return s + b2v;
}

// layer-1 prep for small-graph nodes
DEVFN void small_prep(int node, float xo, float xp,
                      const float* w1s, const float* s1, const float* d1,
                      float* h1s, float* a1s, float* a1d) {
#pragma unroll
  for (int h = 0; h < 3; ++h) {
    float as = 0.f, ad = 0.f;
#pragma unroll
    for (int c = 0; c < 10; ++c) {
      int jj = h * 10 + c;
      float hv = fmaf(xo, w1s[jj], xp * w1s[F1c + jj]);
      h1s[node * F1c + jj] = hv;
      as = fmaf(hv, s1[jj], as);
      ad = fmaf(hv, d1[jj], ad);
    }
    a1s[node * 3 + h] = as;
    a1d[node * 3 + h] = ad;
  }
}

// ------- K_main: Chebyshev folded cos-transform + GAT + decode --------------
// Block = 256 thr = 4 waves = {2 rows x 2 column-halves}. Wave (jrow,half)
// computes cols k = half*128 + 2*lane + q (q=0,1) of row 2*bid+jrow.
// Per t: 1 broadcast ds_read_b64 + 6 FMA per lane. Grid 2048 -> 8192 waves.
__global__ __launch_bounds__(256) void k_main(
    const float* __restrict__ occ, const float* __restrict__ prc,
    const float* __restrict__ W1, const float* __restrict__ b1,
    const float* __restrict__ W2, const float* __restrict__ b2,
    const float* __restrict__ as1, const float* __restrict__ ad1,
    const float* __restrict__ decW, const float* __restrict__ decb,
    float* __restrict__ out, float* __restrict__ vsm,
    float* __restrict__ h1s, float* __restrict__ a1s, float* __restrict__ a1d) {
  __shared__ float y[2][TT + 1][2];       // folded inputs + x[256] at slot 256
  __shared__ float wl[192];               // W1(60) b1(30) W2(30) as1(30) ad1(30)
  __shared__ float decw[4];               // per-wave decode partial
  __shared__ float v256l[2];              // v256 * decW[256] per local row
  const int tid  = threadIdx.x;
  const int lane = tid & 63;
  const int wid  = tid >> 6;
  const int jrow = wid >> 1;              // local row 0..1
  const int half = wid & 1;               // column half 0..1
  const int row  = blockIdx.x * 2 + jrow;

  // stage both rows: thread tid owns t = tid for each row
  {
    const int t = tid;
#pragma unroll
    for (int j = 0; j < 2; ++j) {
      const float* ro = occ + (size_t)(blockIdx.x * 2 + j) * SEQc;
      const float* rp = prc + (size_t)(blockIdx.x * 2 + j) * SEQc;
      float yo, yp;
      if (t == 0) { yo = ro[0]; yp = rp[0]; }
      else        { yo = ro[t] + ro[SEQc - t]; yp = rp[t] + rp[SEQc - t]; }
      y[j][t][0] = yo;
      y[j][t][1] = yp;
      if (t == 0) { y[j][TT][0] = ro[256]; y[j][TT][1] = rp[256]; }
    }
  }
  if      (tid < 60)  wl[tid] = W1[tid];
  else if (tid < 90)  wl[tid] = b1[tid - 60];
  else if (tid < 120) wl[tid] = W2[tid - 90];
  else if (tid < 150) wl[tid] = as1[tid - 120];
  else if (tid < 180) wl[tid] = ad1[tid - 150];
  __syncthreads();
  const float* w1s = wl;
  const float* b1s = wl + 60;
  const float* w2s = wl + 90;
  const float* s1  = wl + 120;
  const float* d1  = wl + 150;

  // seeds: lane owns cols k0, k0+1 ; cos via Chebyshev recurrence
  const int k0 = half * 128 + 2 * lane;
  float m2[2], cc[2], cp[2], acco[2], accp[2];
  {
    float2 y0 = *reinterpret_cast<const float2*>(&y[jrow][0][0]);
#pragma unroll
    for (int q = 0; q < 2; ++q) {
      float c1 = cosf((float)(k0 + q) * (6.283185307179586f / 512.0f));
      m2[q] = 2.f * c1;
      cp[q] = 1.f;
      cc[q] = c1;
      acco[q] = y0.x;                     // t=0 term (cos=1)
      accp[q] = y0.y;
    }
  }
#pragma unroll 8
  for (int t = 1; t < TT; ++t) {
    float2 yv = *reinterpret_cast<const float2*>(&y[jrow][t][0]);
#pragma unroll
    for (int q = 0; q < 2; ++q) {
      acco[q] = fmaf(cc[q], yv.x, acco[q]);
      accp[q] = fmaf(cc[q], yv.y, accp[q]);
      float nx = fmaf(m2[q], cc[q], -cp[q]);
      cp[q] = cc[q];
      cc[q] = nx;
    }
  }

  // epilogue: node values + decode partial over this wave's 128 cols
  const float x256o = y[jrow][TT][0], x256p = y[jrow][TT][1];
  const float b2v = b2[0];
  const bool smallrow = (row < 4);        // rows 0..3 hold nodes < 1024
  const float2 dw2 = *reinterpret_cast<const float2*>(decW + k0);
  const float dwq[2] = {dw2.x, dw2.y};
  float s = 0.f;
#pragma unroll
  for (int q = 0; q < 2; ++q) {
    int k = k0 + q;                       // parity of k == parity of q
    float xo = acco[q] + ((q & 1) ? -x256o : x256o);
    float xp = accp[q] + ((q & 1) ? -x256p : x256p);
    int node = row * FOURc + k;
    float vv = node_v(xo, xp, w1s, b1s, w2s, b2v);
    s = fmaf(vv, dwq[q], s);
    if (smallrow && node < NSMALL) {
      vsm[node] = vv;
      small_prep(node, xo, xp, w1s, s1, d1, h1s, a1s, a1d);
    }
  }
#pragma unroll
  for (int off = 32; off; off >>= 1) s += __shfl_xor(s, off);
  if (lane == 0) decw[wid] = s;

  // k = 256 column: only wave (jrow, half==0)
  if (half == 0) {
    float sgo = 0.f, sgp = 0.f;
#pragma unroll
    for (int m = 0; m < 4; ++m) {
      sgo += y[jrow][lane + 64 * m][0];
      sgp += y[jrow][lane + 64 * m][1];
    }
    float sign = (lane & 1) ? -1.f : 1.f;
    sgo *= sign; sgp *= sign;
#pragma unroll
    for (int off = 32; off; off >>= 1) {
      sgo += __shfl_xor(sgo, off);
      sgp += __shfl_xor(sgp, off);
    }
    if (lane == 0) {
      float xo = sgo + x256o;
      float xp = sgp + x256p;
      float v256 = node_v(xo, xp, w1s, b1s, w2s, b2v);
      v256l[jrow] = v256 * decW[256];
      int node = row * FOURc + 256;
      if (smallrow && node < NSMALL) {
        vsm[node] = v256;
        small_prep(node, xo, xp, w1s, s1, d1, h1s, a1s, a1d);
      }
    }
  }
  __syncthreads();
  if (tid < 2)
    out[blockIdx.x * 2 + tid] = decw[2 * tid] + decw[2 * tid + 1]
                              + v256l[tid] + decb[0];
}

// ------- K_g1: layer-1 gather (one wave per dst) + layer-2 node prep -------
__global__ __launch_bounds__(256) void k_g1(
    const int* __restrict__ cnt, const int* __restrict__ srcs2,
    const float* __restrict__ a1s, const float* __restrict__ a1d,
    const float* __restrict__ h1s,
    const float* __restrict__ b1, const float* __restrict__ W2,
    const float* __restrict__ as2, const float* __restrict__ ad2,
    float* __restrict__ h2s, float* __restrict__ a2s, float* __restrict__ a2d) {
  const int lane = threadIdx.x & 63;
  const int dst  = blockIdx.x * 4 + (threadIdx.x >> 6);
  const int deg  = cnt[dst];
  const int* sp  = srcs2 + dst * CAP;
  const float ad0 = a1d[dst * 3], ad1v = a1d[dst * 3 + 1], ad2v = a1d[dst * 3 + 2];
  float den[3] = {0.f, 0.f, 0.f};
  float num[F1c];
#pragma unroll
  for (int j = 0; j < F1c; ++j) num[j] = 0.f;

  for (int p = lane; p < deg; p += 64) {
    int src = sp[p];
    const float* hs = h1s + src * F1c;
    float x0 = a1s[src * 3]     + ad0;
    float x1 = a1s[src * 3 + 1] + ad1v;
    float x2 = a1s[src * 3 + 2] + ad2v;
    x0 = x0 > 0.f ? x0 : NEG_SLOPE * x0;
    x1 = x1 > 0.f ? x1 : NEG_SLOPE * x1;
    x2 = x2 > 0.f ? x2 : NEG_SLOPE * x2;
    float e0 = __expf(x0), e1 = __expf(x1), e2 = __expf(x2);
    den[0] += e0; den[1] += e1; den[2] += e2;
#pragma unroll
    for (int c = 0; c < 10; ++c) {
      num[c]      = fmaf(e0, hs[c],      num[c]);
      num[10 + c] = fmaf(e1, hs[10 + c], num[10 + c]);
      num[20 + c] = fmaf(e2, hs[20 + c], num[20 + c]);
    }
  }
#pragma unroll
  for (int h = 0; h < 3; ++h)
#pragma unroll
    for (int off = 32; off; off >>= 1) den[h] += __shfl_xor(den[h], off);
#pragma unroll
  for (int j = 0; j < F1c; ++j)
#pragma unroll
    for (int off = 32; off; off >>= 1) num[j] += __shfl_xor(num[j], off);

  if (lane == 0) {
    float h2 = 0.f;
#pragma unroll
    for (int jj = 0; jj < F1c; ++jj) {
      float x2 = num[jj] / den[jj / 10] + b1[jj];
      x2 = x2 > 0.f ? x2 : (__expf(x2) - 1.f);
      h2 = fmaf(x2, W2[jj], h2);
    }
    h2s[dst] = h2;
    a2s[dst] = h2 * as2[0];
    a2d[dst] = h2 * ad2[0];
  }
}

// ------- K_g2: layer-2 gather (one wave per dst) -> final node value -------
__global__ __launch_bounds__(256) void k_g2(
    const int* __restrict__ cnt, const int* __restrict__ srcs2,
    const float* __restrict__ a2s, const float* __restrict__ a2d,
    const float* __restrict__ h2s, const float* __restrict__ b2,
    float* __restrict__ val2) {
  const int lane = threadIdx.x & 63;
  const int dst  = blockIdx.x * 4 + (threadIdx.x >> 6);
  const int deg  = cnt[dst];
  const int* sp  = srcs2 + dst * CAP;
  const float adv = a2d[dst];
  float den = 0.f, num = 0.f;
  for (int p = lane; p < deg; p += 64) {
    int src = sp[p];
    float x = a2s[src] + adv;
    x = x > 0.f ? x : NEG_SLOPE * x;
    float ex = __expf(x);
    den += ex;
    num = fmaf(ex, h2s[src], num);
  }
#pragma unroll
  for (int off = 32; off; off >>= 1) {
    den += __shfl_xor(den, off);
    num += __shfl_xor(num, off);
  }
  if (lane == 0) val2[dst] = num / den + b2[0];
}

// ------- K_tail: correct decode for rows 0..3 -------
__global__ __launch_bounds__(256) void k_tail(
    const float* __restrict__ val2, const float* __restrict__ vsm,
    const float* __restrict__ decW, float* __restrict__ out) {
  const int lane = threadIdx.x & 63;
  const int r    = threadIdx.x >> 6;      // rows 0..3
  float c = 0.f;
  for (int k = lane; k < FOURc; k += 64) {
    int node = r * FOURc + k;
    if (node < NSMALL) c += (val2[node] - vsm[node]) * decW[k];
  }
#pragma unroll
  for (int off = 32; off; off >>= 1) c += __shfl_xor(c, off);
  if (lane == 0) out[r] += c;
}

// ---------------- host launcher ----------------
extern "C" void kernel_launch(void* const* d_in, const int* in_sizes, int n_in,
                              void* d_out, int out_size, void* d_ws, size_t ws_size,
                              hipStream_t stream) {
  const float* occ  = (const float*)d_in[0];
  const float* prc  = (const float*)d_in[1];
  const int*   ei   = (const int*)d_in[2];
  const float* W1   = (const float*)d_in[3];
  const float* as1  = (const float*)d_in[4];
  const float* ad1  = (const float*)d_in[5];
  const float* b1   = (const float*)d_in[6];
  const float* W2   = (const float*)d_in[7];
  const float* as2  = (const float*)d_in[8];
  const float* ad2  = (const float*)d_in[9];
  const float* b2   = (const float*)d_in[10];
  const float* decW = (const float*)d_in[11];
  const float* decb = (const float*)d_in[12];
  const int E = in_sizes[2] / 2;

  float* ws = (float*)d_ws;
  float* h1s  = ws;                       // 1024*30
  float* a1s  = h1s + NSMALL * F1c;       // 1024*3
  float* a1d  = a1s + NSMALL * 3;         // 1024*3
  float* h2s  = a1d + NSMALL * 3;         // 1024
  float* a2s  = h2s + NSMALL;             // 1024
  float* a2d  = a2s + NSMALL;             // 1024
  float* val2 = a2d + NSMALL;             // 1024
  float* vsm  = val2 + NSMALL;            // 1024
  int*   cnt  = (int*)(vsm + NSMALL);     // 1024
  int*   srcs2 = cnt + NSMALL;            // 1024*CAP

  // zero bucket counters (graph-capturable memset node)
  hipMemsetAsync(cnt, 0, NSMALL * sizeof(int), stream);

  // K_pre: parallel bucket scatter
  k_pre<<<32, 256, 0, stream>>>(ei, E, cnt, srcs2);

  // K_main: recurrence transform, 2 rows x 2 halves per block (8192 waves)
  k_main<<<NROWS / 2, 256, 0, stream>>>(occ, prc, W1, b1, W2, b2, as1, ad1,
                                        decW, decb, (float*)d_out, vsm,
                                        h1s, a1s, a1d);

  // small-graph gathers (no atomics)
  k_g1<<<NSMALL / 4, 256, 0, stream>>>(cnt, srcs2, a1s, a1d, h1s,
                                       b1, W2, as2, ad2, h2s, a2s, a2d);
  k_g2<<<NSMALL / 4, 256, 0, stream>>>(cnt, srcs2, a2s, a2d, h2s, b2, val2);

  // fix rows 0..3
  k_tail<<<1, 256, 0, stream>>>(val2, vsm, decW, (float*)d_out);
}

// Round 12
// 69.385 us; speedup vs baseline: 1.0787x; 1.0787x over previous
//
#include <hip/hip_runtime.h>
#include <math.h>

// ---- problem constants (fixed by reference setup) ----
constexpr int Bc    = 4;
constexpr int Nc    = 1024;
constexpr int SEQc  = 512;
constexpr int FOURc = 257;              // rfft output length
constexpr int NROWS = Bc * Nc;          // 4096 (b,n) rows
constexpr int NSMALL = 1024;            // nodes touched by real edges
constexpr int F1c   = 30;               // H1*C1
constexpr int TT    = 256;              // folded t length
constexpr int CAP   = 128;              // max in-degree bucket capacity
constexpr int XPAD  = 258;              // xf row stride (pad for 16B alignment)
constexpr float NEG_SLOPE = 0.2f;

#define DEVFN static __device__ __forceinline__

// ------- K_pre: parallel bucket scatter (CSR-lite), 32 blocks -------
__global__ __launch_bounds__(256) void k_pre(const int* __restrict__ ei, int E,
                                             int* __restrict__ cnt,
                                             int* __restrict__ srcs2) {
  const int base = blockIdx.x * 256 + threadIdx.x;
  const int tot  = E + NSMALL;
  for (int e = base; e < tot; e += 32 * 256) {
    int src, dst;
    if (e < E) { src = ei[e]; dst = ei[E + e]; }
    else       { src = dst = e - E; }     // self loops
    int pos = atomicAdd(&cnt[dst], 1);
    if (pos < CAP) srcs2[dst * CAP + pos] = src;
  }
}

// self-loop-only node value: v = elu(xf@W1 + b1) @ W2 + b2
DEVFN float node_v(float xo, float xp,
                   const float* w1s, const float* b1s, const float* w2s, float b2v) {
  float s = 0.f;
#pragma unroll
  for (int jj = 0; jj < F1c; ++jj) {
    float h = fmaf(xo, w1s[jj], fmaf(xp, w1s[F1c + jj], b1s[jj]));
    float e = h > 0.f ? h : (__expf(h) - 1.f);
    s = fmaf(e, w2s[jj], s);
  }
  return s + b2v;
}

// layer-1 prep for small-graph nodes
DEVFN void small_prep(int node, float xo, float xp,
                      const float* w1s, const float* s1, const float* d1,
                      float* h1s, float* a1s, float* a1d) {
#pragma unroll
  for (int h = 0; h < 3; ++h) {
    float as = 0.f, ad = 0.f;
#pragma unroll
    for (int c = 0; c < 10; ++c) {
      int jj = h * 10 + c;
      float hv = fmaf(xo, w1s[jj], xp * w1s[F1c + jj]);
      h1s[node * F1c + jj] = hv;
      as = fmaf(hv, s1[jj], as);
      ad = fmaf(hv, d1[jj], ad);
    }
    a1s[node * 3 + h] = as;
    a1d[node * 3 + h] = ad;
  }
}

// ------- K_xf: pure Chebyshev folded cos-transform -> xf buffer -------------
// Block = 256 thr = 4 waves = {2 rows x 2 column-halves}. Wave (jrow,half)
// computes cols k = half*128 + 2*lane + q (q=0,1) of row 2*bid+jrow.
// No heavy epilogue -> low VGPR -> high residency. Stores xf as float2/node.
__global__ __launch_bounds__(256) void k_xf(
    const float* __restrict__ occ, const float* __restrict__ prc,
    float* __restrict__ xf) {
  __shared__ float y[2][TT + 1][2];       // folded inputs + x[256] at slot 256
  const int tid  = threadIdx.x;
  const int lane = tid & 63;
  const int wid  = tid >> 6;
  const int jrow = wid >> 1;              // local row 0..1
  const int half = wid & 1;               // column half 0..1
  const int row  = blockIdx.x * 2 + jrow;

  // stage both rows: thread tid owns t = tid for each row
  {
    const int t = tid;
#pragma unroll
    for (int j = 0; j < 2; ++j) {
      const float* ro = occ + (size_t)(blockIdx.x * 2 + j) * SEQc;
      const float* rp = prc + (size_t)(blockIdx.x * 2 + j) * SEQc;
      float yo, yp;
      if (t == 0) { yo = ro[0]; yp = rp[0]; }
      else        { yo = ro[t] + ro[SEQc - t]; yp = rp[t] + rp[SEQc - t]; }
      y[j][t][0] = yo;
      y[j][t][1] = yp;
      if (t == 0) { y[j][TT][0] = ro[256]; y[j][TT][1] = rp[256]; }
    }
  }
  __syncthreads();

  // seeds: lane owns cols k0, k0+1 ; cos via Chebyshev recurrence
  const int k0 = half * 128 + 2 * lane;
  float m2[2], cc[2], cp[2], acco[2], accp[2];
  {
    float2 y0 = *reinterpret_cast<const float2*>(&y[jrow][0][0]);
#pragma unroll
    for (int q = 0; q < 2; ++q) {
      float c1 = cosf((float)(k0 + q) * (6.283185307179586f / 512.0f));
      m2[q] = 2.f * c1;
      cp[q] = 1.f;
      cc[q] = c1;
      acco[q] = y0.x;                     // t=0 term (cos=1)
      accp[q] = y0.y;
    }
  }
#pragma unroll 8
  for (int t = 1; t < TT; ++t) {
    float2 yv = *reinterpret_cast<const float2*>(&y[jrow][t][0]);
#pragma unroll
    for (int q = 0; q < 2; ++q) {
      acco[q] = fmaf(cc[q], yv.x, acco[q]);
      accp[q] = fmaf(cc[q], yv.y, accp[q]);
      float nx = fmaf(m2[q], cc[q], -cp[q]);
      cp[q] = cc[q];
      cc[q] = nx;
    }
  }

  // x[256] correction: xf[k] += (-1)^k x256 ; store 2 nodes as one float4
  const float x256o = y[jrow][TT][0], x256p = y[jrow][TT][1];
  float4 st;                              // k0 even, k0+1 odd
  st.x = acco[0] + x256o;
  st.y = accp[0] + x256p;
  st.z = acco[1] - x256o;
  st.w = accp[1] - x256p;
  *reinterpret_cast<float4*>(xf + ((size_t)row * XPAD + k0) * 2) = st;

  // k = 256 column: only wave (jrow, half==0)
  if (half == 0) {
    float sgo = 0.f, sgp = 0.f;
#pragma unroll
    for (int m = 0; m < 4; ++m) {
      sgo += y[jrow][lane + 64 * m][0];
      sgp += y[jrow][lane + 64 * m][1];
    }
    float sign = (lane & 1) ? -1.f : 1.f;
    sgo *= sign; sgp *= sign;
#pragma unroll
    for (int off = 32; off; off >>= 1) {
      sgo += __shfl_xor(sgo, off);
      sgp += __shfl_xor(sgp, off);
    }
    if (lane == 0) {
      float2 st2;
      st2.x = sgo + x256o;
      st2.y = sgp + x256p;
      *reinterpret_cast<float2*>(xf + ((size_t)row * XPAD + 256) * 2) = st2;
    }
  }
}

// ------- K_post: node_v + fused decode + small-graph prep ------------------
// One block per row (256 thr); thread tid = col tid; tid 0 also col 256.
__global__ __launch_bounds__(256) void k_post(
    const float* __restrict__ xf,
    const float* __restrict__ W1, const float* __restrict__ b1,
    const float* __restrict__ W2, const float* __restrict__ b2,
    const float* __restrict__ as1, const float* __restrict__ ad1,
    const float* __restrict__ decW, const float* __restrict__ decb,
    float* __restrict__ out, float* __restrict__ vsm,
    float* __restrict__ h1s, float* __restrict__ a1s, float* __restrict__ a1d) {
  __shared__ float wl[192];               // W1(60) b1(30) W2(30) as1(30) ad1(30)
  __shared__ float red[4];
  const int tid = threadIdx.x;
  const int row = blockIdx.x;
  if      (tid < 60)  wl[tid] = W1[tid];
  else if (tid < 90)  wl[tid] = b1[tid - 60];
  else if (tid < 120) wl[tid] = W2[tid - 90];
  else if (tid < 150) wl[tid] = as1[tid - 120];
  else if (tid < 180) wl[tid] = ad1[tid - 150];
  __syncthreads();
  const float* w1s = wl;
  const float* b1s = wl + 60;
  const float* w2s = wl + 90;
  const float* s1  = wl + 120;
  const float* d1  = wl + 150;
  const float b2v  = b2[0];
  const bool smallrow = (row < 4);

  float2 v2 = *reinterpret_cast<const float2*>(xf + ((size_t)row * XPAD + tid) * 2);
  float vv = node_v(v2.x, v2.y, w1s, b1s, w2s, b2v);
  float s = vv * decW[tid];
  if (tid == 0) {                         // col 256
    float2 v6 = *reinterpret_cast<const float2*>(xf + ((size_t)row * XPAD + 256) * 2);
    float v256 = node_v(v6.x, v6.y, w1s, b1s, w2s, b2v);
    s = fmaf(v256, decW[256], s);
    if (smallrow) {
      int node = row * FOURc + 256;
      if (node < NSMALL) {
        vsm[node] = v256;
        small_prep(node, v6.x, v6.y, w1s, s1, d1, h1s, a1s, a1d);
      }
    }
  }
  if (smallrow) {
    int node = row * FOURc + tid;
    if (node < NSMALL) {
      vsm[node] = vv;
      small_prep(node, v2.x, v2.y, w1s, s1, d1, h1s, a1s, a1d);
    }
  }
#pragma unroll
  for (int off = 32; off; off >>= 1) s += __shfl_xor(s, off);
  if ((tid & 63) == 0) red[tid >> 6] = s;
  __syncthreads();
  if (tid == 0) out[row] = red[0] + red[1] + red[2] + red[3] + decb[0];
}

// ------- K_g1: layer-1 gather (one wave per dst) + layer-2 node prep -------
__global__ __launch_bounds__(256) void k_g1(
    const int* __restrict__ cnt, const int* __restrict__ srcs2,
    const float* __restrict__ a1s, const float* __restrict__ a1d,
    const float* __restrict__ h1s,
    const float* __restrict__ b1, const float* __restrict__ W2,
    const float* __restrict__ as2, const float* __restrict__ ad2,
    float* __restrict__ h2s, float* __restrict__ a2s, float* __restrict__ a2d) {
  const int lane = threadIdx.x & 63;
  const int dst  = blockIdx.x * 4 + (threadIdx.x >> 6);
  const int deg  = cnt[dst];
  const int* sp  = srcs2 + dst * CAP;
  const float ad0 = a1d[dst * 3], ad1v = a1d[dst * 3 + 1], ad2v = a1d[dst * 3 + 2];
  float den[3] = {0.f, 0.f, 0.f};
  float num[F1c];
#pragma unroll
  for (int j = 0; j < F1c; ++j) num[j] = 0.f;

  for (int p = lane; p < deg; p += 64) {
    int src = sp[p];
    const float* hs = h1s + src * F1c;
    float x0 = a1s[src * 3]     + ad0;
    float x1 = a1s[src * 3 + 1] + ad1v;
    float x2 = a1s[src * 3 + 2] + ad2v;
    x0 = x0 > 0.f ? x0 : NEG_SLOPE * x0;
    x1 = x1 > 0.f ? x1 : NEG_SLOPE * x1;
    x2 = x2 > 0.f ? x2 : NEG_SLOPE * x2;
    float e0 = __expf(x0), e1 = __expf(x1), e2 = __expf(x2);
    den[0] += e0; den[1] += e1; den[2] += e2;
#pragma unroll
    for (int c = 0; c < 10; ++c) {
      num[c]      = fmaf(e0, hs[c],      num[c]);
      num[10 + c] = fmaf(e1, hs[10 + c], num[10 + c]);
      num[20 + c] = fmaf(e2, hs[20 + c], num[20 + c]);
    }
  }
#pragma unroll
  for (int h = 0; h < 3; ++h)
#pragma unroll
    for (int off = 32; off; off >>= 1) den[h] += __shfl_xor(den[h], off);
#pragma unroll
  for (int j = 0; j < F1c; ++j)
#pragma unroll
    for (int off = 32; off; off >>= 1) num[j] += __shfl_xor(num[j], off);

  if (lane == 0) {
    float h2 = 0.f;
#pragma unroll
    for (int jj = 0; jj < F1c; ++jj) {
      float x2 = num[jj] / den[jj / 10] + b1[jj];
      x2 = x2 > 0.f ? x2 : (__expf(x2) - 1.f);
      h2 = fmaf(x2, W2[jj], h2);
    }
    h2s[dst] = h2;
    a2s[dst] = h2 * as2[0];
    a2d[dst] = h2 * ad2[0];
  }
}

// ------- K_g2: layer-2 gather (one wave per dst) -> final node value -------
__global__ __launch_bounds__(256) void k_g2(
    const int* __restrict__ cnt, const int* __restrict__ srcs2,
    const float* __restrict__ a2s, const float* __restrict__ a2d,
    const float* __restrict__ h2s, const float* __restrict__ b2,
    float* __restrict__ val2) {
  const int lane = threadIdx.x & 63;
  const int dst  = blockIdx.x * 4 + (threadIdx.x >> 6);
  const int deg  = cnt[dst];
  const int* sp  = srcs2 + dst * CAP;
  const float adv = a2d[dst];
  float den = 0.f, num = 0.f;
  for (int p = lane; p < deg; p += 64) {
    int src = sp[p];
    float x = a2s[src] + adv;
    x = x > 0.f ? x : NEG_SLOPE * x;
    float ex = __expf(x);
    den += ex;
    num = fmaf(ex, h2s[src], num);
  }
#pragma unroll
  for (int off = 32; off; off >>= 1) {
    den += __shfl_xor(den, off);
    num += __shfl_xor(num, off);
  }
  if (lane == 0) val2[dst] = num / den + b2[0];
}

// ------- K_tail: correct decode for rows 0..3 -------
__global__ __launch_bounds__(256) void k_tail(
    const float* __restrict__ val2, const float* __restrict__ vsm,
    const float* __restrict__ decW, float* __restrict__ out) {
  const int lane = threadIdx.x & 63;
  const int r    = threadIdx.x >> 6;      // rows 0..3
  float c = 0.f;
  for (int k = lane; k < FOURc; k += 64) {
    int node = r * FOURc + k;
    if (node < NSMALL) c += (val2[node] - vsm[node]) * decW[k];
  }
#pragma unroll
  for (int off = 32; off; off >>= 1) c += __shfl_xor(c, off);
  if (lane == 0) out[r] += c;
}

// ---------------- host launcher ----------------
extern "C" void kernel_launch(void* const* d_in, const int* in_sizes, int n_in,
                              void* d_out, int out_size, void* d_ws, size_t ws_size,
                              hipStream_t stream) {
  const float* occ  = (const float*)d_in[0];
  const float* prc  = (const float*)d_in[1];
  const int*   ei   = (const int*)d_in[2];
  const float* W1   = (const float*)d_in[3];
  const float* as1  = (const float*)d_in[4];
  const float* ad1  = (const float*)d_in[5];
  const float* b1   = (const float*)d_in[6];
  const float* W2   = (const float*)d_in[7];
  const float* as2  = (const float*)d_in[8];
  const float* ad2  = (const float*)d_in[9];
  const float* b2   = (const float*)d_in[10];
  const float* decW = (const float*)d_in[11];
  const float* decb = (const float*)d_in[12];
  const int E = in_sizes[2] / 2;

  float* ws = (float*)d_ws;
  float* xf   = ws;                       // NROWS * XPAD * 2 = 2,113,536
  float* h1s  = xf + (size_t)NROWS * XPAD * 2;  // 1024*30
  float* a1s  = h1s + NSMALL * F1c;       // 1024*3
  float* a1d  = a1s + NSMALL * 3;         // 1024*3
  float* h2s  = a1d + NSMALL * 3;         // 1024
  float* a2s  = h2s + NSMALL;             // 1024
  float* a2d  = a2s + NSMALL;             // 1024
  float* val2 = a2d + NSMALL;             // 1024
  float* vsm  = val2 + NSMALL;            // 1024
  int*   cnt  = (int*)(vsm + NSMALL);     // 1024
  int*   srcs2 = cnt + NSMALL;            // 1024*CAP

  // zero bucket counters (graph-capturable memset node)
  hipMemsetAsync(cnt, 0, NSMALL * sizeof(int), stream);

  // K_pre: parallel bucket scatter
  k_pre<<<32, 256, 0, stream>>>(ei, E, cnt, srcs2);

  // K_xf: pure recurrence transform (low VGPR, 8192 waves)
  k_xf<<<NROWS / 2, 256, 0, stream>>>(occ, prc, xf);

  // K_post: node_v + decode + small-graph prep (one block per row)
  k_post<<<NROWS, 256, 0, stream>>>(xf, W1, b1, W2, b2, as1, ad1,
                                    decW, decb, (float*)d_out, vsm,
                                    h1s, a1s, a1d);

  // small-graph gathers (no atomics)
  k_g1<<<NSMALL / 4, 256, 0, stream>>>(cnt, srcs2, a1s, a1d, h1s,
                                       b1, W2, as2, ad2, h2s, a2s, a2d);
  k_g2<<<NSMALL / 4, 256, 0, stream>>>(cnt, srcs2, a2s, a2d, h2s, b2, val2);

  // fix rows 0..3
  k_tail<<<1, 256, 0, stream>>>(val2, vsm, decW, (float*)d_out);
}

// Round 13
// 65.005 us; speedup vs baseline: 1.1514x; 1.0674x over previous
//
#include <hip/hip_runtime.h>
#include <math.h>

// ---- problem constants (fixed by reference setup) ----
constexpr int Bc    = 4;
constexpr int Nc    = 1024;
constexpr int SEQc  = 512;
constexpr int FOURc = 257;              // rfft output length
constexpr int NROWS = Bc * Nc;          // 4096 (b,n) rows
constexpr int NSMALL = 1024;            // nodes touched by real edges
constexpr int F1c   = 30;               // H1*C1
constexpr int TT    = 256;              // folded t length
constexpr int CAP   = 128;              // max in-degree bucket capacity
constexpr int XPAD  = 258;              // xf row stride (pad for 16B alignment)
constexpr float NEG_SLOPE = 0.2f;

#define DEVFN static __device__ __forceinline__

// ------- K_xf: pure Chebyshev folded cos-transform -> xf buffer -------------
// Block = 256 thr = 4 waves = {2 rows x 2 column-halves}. Wave (jrow,half)
// computes cols k = half*128 + 2*lane + q (q=0,1) of row 2*bid+jrow.
// Block 0 additionally zeroes the bucket counters for k_pre (which runs
// after k_xf on the same stream -> ordering guaranteed). No hipMemsetAsync:
// the rocclr fillBuffer dispatch for 4 KB was costing ~40 us (r12 profile).
__global__ __launch_bounds__(256) void k_xf(
    const float* __restrict__ occ, const float* __restrict__ prc,
    float* __restrict__ xf, int* __restrict__ cnt) {
  __shared__ float y[2][TT + 1][2];       // folded inputs + x[256] at slot 256
  const int tid  = threadIdx.x;
  const int lane = tid & 63;
  const int wid  = tid >> 6;
  const int jrow = wid >> 1;              // local row 0..1
  const int half = wid & 1;               // column half 0..1
  const int row  = blockIdx.x * 2 + jrow;

  if (blockIdx.x == 0) {                  // zero bucket counters for k_pre
#pragma unroll
    for (int j = 0; j < 4; ++j) cnt[tid + 256 * j] = 0;
  }

  // stage both rows: thread tid owns t = tid for each row
  {
    const int t = tid;
#pragma unroll
    for (int j = 0; j < 2; ++j) {
      const float* ro = occ + (size_t)(blockIdx.x * 2 + j) * SEQc;
      const float* rp = prc + (size_t)(blockIdx.x * 2 + j) * SEQc;
      float yo, yp;
      if (t == 0) { yo = ro[0]; yp = rp[0]; }
      else        { yo = ro[t] + ro[SEQc - t]; yp = rp[t] + rp[SEQc - t]; }
      y[j][t][0] = yo;
      y[j][t][1] = yp;
      if (t == 0) { y[j][TT][0] = ro[256]; y[j][TT][1] = rp[256]; }
    }
  }
  __syncthreads();

  // seeds: lane owns cols k0, k0+1 ; cos via Chebyshev recurrence
  const int k0 = half * 128 + 2 * lane;
  float m2[2], cc[2], cp[2], acco[2], accp[2];
  {
    float2 y0 = *reinterpret_cast<const float2*>(&y[jrow][0][0]);
#pragma unroll
    for (int q = 0; q < 2; ++q) {
      float c1 = cosf((float)(k0 + q) * (6.283185307179586f / 512.0f));
      m2[q] = 2.f * c1;
      cp[q] = 1.f;
      cc[q] = c1;
      acco[q] = y0.x;                     // t=0 term (cos=1)
      accp[q] = y0.y;
    }
  }
#pragma unroll 8
  for (int t = 1; t < TT; ++t) {
    float2 yv = *reinterpret_cast<const float2*>(&y[jrow][t][0]);
#pragma unroll
    for (int q = 0; q < 2; ++q) {
      acco[q] = fmaf(cc[q], yv.x, acco[q]);
      accp[q] = fmaf(cc[q], yv.y, accp[q]);
      float nx = fmaf(m2[q], cc[q], -cp[q]);
      cp[q] = cc[q];
      cc[q] = nx;
    }
  }

  // x[256] correction: xf[k] += (-1)^k x256 ; store 2 nodes as one float4
  const float x256o = y[jrow][TT][0], x256p = y[jrow][TT][1];
  float4 st;                              // k0 even, k0+1 odd
  st.x = acco[0] + x256o;
  st.y = accp[0] + x256p;
  st.z = acco[1] - x256o;
  st.w = accp[1] - x256p;
  *reinterpret_cast<float4*>(xf + ((size_t)row * XPAD + k0) * 2) = st;

  // k = 256 column: only wave (jrow, half==0)
  if (half == 0) {
    float sgo = 0.f, sgp = 0.f;
#pragma unroll
    for (int m = 0; m < 4; ++m) {
      sgo += y[jrow][lane + 64 * m][0];
      sgp += y[jrow][lane + 64 * m][1];
    }
    float sign = (lane & 1) ? -1.f : 1.f;
    sgo *= sign; sgp *= sign;
#pragma unroll
    for (int off = 32; off; off >>= 1) {
      sgo += __shfl_xor(sgo, off);
      sgp += __shfl_xor(sgp, off);
    }
    if (lane == 0) {
      float2 st2;
      st2.x = sgo + x256o;
      st2.y = sgp + x256p;
      *reinterpret_cast<float2*>(xf + ((size_t)row * XPAD + 256) * 2) = st2;
    }
  }
}

// ------- K_pre: parallel bucket scatter (CSR-lite), 32 blocks -------
__global__ __launch_bounds__(256) void k_pre(const int* __restrict__ ei, int E,
                                             int* __restrict__ cnt,
                                             int* __restrict__ srcs2) {
  const int base = blockIdx.x * 256 + threadIdx.x;
  const int tot  = E + NSMALL;
  for (int e = base; e < tot; e += 32 * 256) {
    int src, dst;
    if (e < E) { src = ei[e]; dst = ei[E + e]; }
    else       { src = dst = e - E; }     // self loops
    int pos = atomicAdd(&cnt[dst], 1);
    if (pos < CAP) srcs2[dst * CAP + pos] = src;
  }
}

// self-loop-only node value: v = elu(xf@W1 + b1) @ W2 + b2
DEVFN float node_v(float xo, float xp,
                   const float* w1s, const float* b1s, const float* w2s, float b2v) {
  float s = 0.f;
#pragma unroll
  for (int jj = 0; jj < F1c; ++jj) {
    float h = fmaf(xo, w1s[jj], fmaf(xp, w1s[F1c + jj], b1s[jj]));
    float e = h > 0.f ? h : (__expf(h) - 1.f);
    s = fmaf(e, w2s[jj], s);
  }
  return s + b2v;
}

// layer-1 prep for small-graph nodes
DEVFN void small_prep(int node, float xo, float xp,
                      const float* w1s, const float* s1, const float* d1,
                      float* h1s, float* a1s, float* a1d) {
#pragma unroll
  for (int h = 0; h < 3; ++h) {
    float as = 0.f, ad = 0.f;
#pragma unroll
    for (int c = 0; c < 10; ++c) {
      int jj = h * 10 + c;
      float hv = fmaf(xo, w1s[jj], xp * w1s[F1c + jj]);
      h1s[node * F1c + jj] = hv;
      as = fmaf(hv, s1[jj], as);
      ad = fmaf(hv, d1[jj], ad);
    }
    a1s[node * 3 + h] = as;
    a1d[node * 3 + h] = ad;
  }
}

// ------- K_post: node_v + fused decode + small-graph prep ------------------
// One block per row (256 thr); thread tid = col tid; tid 0 also col 256.
__global__ __launch_bounds__(256) void k_post(
    const float* __restrict__ xf,
    const float* __restrict__ W1, const float* __restrict__ b1,
    const float* __restrict__ W2, const float* __restrict__ b2,
    const float* __restrict__ as1, const float* __restrict__ ad1,
    const float* __restrict__ decW, const float* __restrict__ decb,
    float* __restrict__ out, float* __restrict__ vsm,
    float* __restrict__ h1s, float* __restrict__ a1s, float* __restrict__ a1d) {
  __shared__ float wl[192];               // W1(60) b1(30) W2(30) as1(30) ad1(30)
  __shared__ float red[4];
  const int tid = threadIdx.x;
  const int row = blockIdx.x;
  if      (tid < 60)  wl[tid] = W1[tid];
  else if (tid < 90)  wl[tid] = b1[tid - 60];
  else if (tid < 120) wl[tid] = W2[tid - 90];
  else if (tid < 150) wl[tid] = as1[tid - 120];
  else if (tid < 180) wl[tid] = ad1[tid - 150];
  __syncthreads();
  const float* w1s = wl;
  const float* b1s = wl + 60;
  const float* w2s = wl + 90;
  const float* s1  = wl + 120;
  const float* d1  = wl + 150;
  const float b2v  = b2[0];
  const bool smallrow = (row < 4);

  float2 v2 = *reinterpret_cast<const float2*>(xf + ((size_t)row * XPAD + tid) * 2);
  float vv = node_v(v2.x, v2.y, w1s, b1s, w2s, b2v);
  float s = vv * decW[tid];
  if (tid == 0) {                         // col 256
    float2 v6 = *reinterpret_cast<const float2*>(xf + ((size_t)row * XPAD + 256) * 2);
    float v256 = node_v(v6.x, v6.y, w1s, b1s, w2s, b2v);
    s = fmaf(v256, decW[256], s);
    if (smallrow) {
      int node = row * FOURc + 256;
      if (node < NSMALL) {
        vsm[node] = v256;
        small_prep(node, v6.x, v6.y, w1s, s1, d1, h1s, a1s, a1d);
      }
    }
  }
  if (smallrow) {
    int node = row * FOURc + tid;
    if (node < NSMALL) {
      vsm[node] = vv;
      small_prep(node, v2.x, v2.y, w1s, s1, d1, h1s, a1s, a1d);
    }
  }
#pragma unroll
  for (int off = 32; off; off >>= 1) s += __shfl_xor(s, off);
  if ((tid & 63) == 0) red[tid >> 6] = s;
  __syncthreads();
  if (tid == 0) out[row] = red[0] + red[1] + red[2] + red[3] + decb[0];
}

// ------- K_g1: layer-1 gather (one wave per dst) + layer-2 node prep -------
__global__ __launch_bounds__(256) void k_g1(
    const int* __restrict__ cnt, const int* __restrict__ srcs2,
    const float* __restrict__ a1s, const float* __restrict__ a1d,
    const float* __restrict__ h1s,
    const float* __restrict__ b1, const float* __restrict__ W2,
    const float* __restrict__ as2, const float* __restrict__ ad2,
    float* __restrict__ h2s, float* __restrict__ a2s, float* __restrict__ a2d) {
  const int lane = threadIdx.x & 63;
  const int dst  = blockIdx.x * 4 + (threadIdx.x >> 6);
  const int deg  = cnt[dst];
  const int* sp  = srcs2 + dst * CAP;
  const float ad0 = a1d[dst * 3], ad1v = a1d[dst * 3 + 1], ad2v = a1d[dst * 3 + 2];
  float den[3] = {0.f, 0.f, 0.f};
  float num[F1c];
#pragma unroll
  for (int j = 0; j < F1c; ++j) num[j] = 0.f;

  for (int p = lane; p < deg; p += 64) {
    int src = sp[p];
    const float* hs = h1s + src * F1c;
    float x0 = a1s[src * 3]     + ad0;
    float x1 = a1s[src * 3 + 1] + ad1v;
    float x2 = a1s[src * 3 + 2] + ad2v;
    x0 = x0 > 0.f ? x0 : NEG_SLOPE * x0;
    x1 = x1 > 0.f ? x1 : NEG_SLOPE * x1;
    x2 = x2 > 0.f ? x2 : NEG_SLOPE * x2;
    float e0 = __expf(x0), e1 = __expf(x1), e2 = __expf(x2);
    den[0] += e0; den[1] += e1; den[2] += e2;
#pragma unroll
    for (int c = 0; c < 10; ++c) {
      num[c]      = fmaf(e0, hs[c],      num[c]);
      num[10 + c] = fmaf(e1, hs[10 + c], num[10 + c]);
      num[20 + c] = fmaf(e2, hs[20 + c], num[20 + c]);
    }
  }
#pragma unroll
  for (int h = 0; h < 3; ++h)
#pragma unroll
    for (int off = 32; off; off >>= 1) den[h] += __shfl_xor(den[h], off);
#pragma unroll
  for (int j = 0; j < F1c; ++j)
#pragma unroll
    for (int off = 32; off; off >>= 1) num[j] += __shfl_xor(num[j], off);

  if (lane == 0) {
    float h2 = 0.f;
#pragma unroll
    for (int jj = 0; jj < F1c; ++jj) {
      float x2 = num[jj] / den[jj / 10] + b1[jj];
      x2 = x2 > 0.f ? x2 : (__expf(x2) - 1.f);
      h2 = fmaf(x2, W2[jj], h2);
    }
    h2s[dst] = h2;
    a2s[dst] = h2 * as2[0];
    a2d[dst] = h2 * ad2[0];
  }
}

// ------- K_g2: layer-2 gather (one wave per dst) -> final node value -------
__global__ __launch_bounds__(256) void k_g2(
    const int* __restrict__ cnt, const int* __restrict__ srcs2,
    const float* __restrict__ a2s, const float* __restrict__ a2d,
    const float* __restrict__ h2s, const float* __restrict__ b2,
    float* __restrict__ val2) {
  const int lane = threadIdx.x & 63;
  const int dst  = blockIdx.x * 4 + (threadIdx.x >> 6);
  const int deg  = cnt[dst];
  const int* sp  = srcs2 + dst * CAP;
  const float adv = a2d[dst];
  float den = 0.f, num = 0.f;
  for (int p = lane; p < deg; p += 64) {
    int src = sp[p];
    float x = a2s[src] + adv;
    x = x > 0.f ? x : NEG_SLOPE * x;
    float ex = __expf(x);
    den += ex;
    num = fmaf(ex, h2s[src], num);
  }
#pragma unroll
  for (int off = 32; off; off >>= 1) {
    den += __shfl_xor(den, off);
    num += __shfl_xor(num, off);
  }
  if (lane == 0) val2[dst] = num / den + b2[0];
}

// ------- K_tail: correct decode for rows 0..3 -------
__global__ __launch_bounds__(256) void k_tail(
    const float* __restrict__ val2, const float* __restrict__ vsm,
    const float* __restrict__ decW, float* __restrict__ out) {
  const int lane = threadIdx.x & 63;
  const int r    = threadIdx.x >> 6;      // rows 0..3
  float c = 0.f;
  for (int k = lane; k < FOURc; k += 64) {
    int node = r * FOURc + k;
    if (node < NSMALL) c += (val2[node] - vsm[node]) * decW[k];
  }
#pragma unroll
  for (int off = 32; off; off >>= 1) c += __shfl_xor(c, off);
  if (lane == 0) out[r] += c;
}

// ---------------- host launcher ----------------
extern "C" void kernel_launch(void* const* d_in, const int* in_sizes, int n_in,
                              void* d_out, int out_size, void* d_ws, size_t ws_size,
                              hipStream_t stream) {
  const float* occ  = (const float*)d_in[0];
  const float* prc  = (const float*)d_in[1];
  const int*   ei   = (const int*)d_in[2];
  const float* W1   = (const float*)d_in[3];
  const float* as1  = (const float*)d_in[4];
  const float* ad1  = (const float*)d_in[5];
  const float* b1   = (const float*)d_in[6];
  const float* W2   = (const float*)d_in[7];
  const float* as2  = (const float*)d_in[8];
  const float* ad2  = (const float*)d_in[9];
  const float* b2   = (const float*)d_in[10];
  const float* decW = (const float*)d_in[11];
  const float* decb = (const float*)d_in[12];
  const int E = in_sizes[2] / 2;

  float* ws = (float*)d_ws;
  float* xf   = ws;                       // NROWS * XPAD * 2 = 2,113,536
  float* h1s  = xf + (size_t)NROWS * XPAD * 2;  // 1024*30
  float* a1s  = h1s + NSMALL * F1c;       // 1024*3
  float* a1d  = a1s + NSMALL * 3;         // 1024*3
  float* h2s  = a1d + NSMALL * 3;         // 1024
  float* a2s  = h2s + NSMALL;             // 1024
  float* a2d  = a2s + NSMALL;             // 1024
  float* val2 = a2d + NSMALL;             // 1024
  float* vsm  = val2 + NSMALL;            // 1024
  int*   cnt  = (int*)(vsm + NSMALL);     // 1024
  int*   srcs2 = cnt + NSMALL;            // 1024*CAP

  // K_xf: pure recurrence transform (block 0 zeroes cnt for k_pre)
  k_xf<<<NROWS / 2, 256, 0, stream>>>(occ, prc, xf, cnt);

  // K_pre: parallel bucket scatter (cnt zeroed by k_xf, stream-ordered)
  k_pre<<<32, 256, 0, stream>>>(ei, E, cnt, srcs2);

  // K_post: node_v + decode + small-graph prep (one block per row)
  k_post<<<NROWS, 256, 0, stream>>>(xf, W1, b1, W2, b2, as1, ad1,
                                    decW, decb, (float*)d_out, vsm,
                                    h1s, a1s, a1d);

  // small-graph gathers (no atomics)
  k_g1<<<NSMALL / 4, 256, 0, stream>>>(cnt, srcs2, a1s, a1d, h1s,
                                       b1, W2, as2, ad2, h2s, a2s, a2d);
  k_g2<<<NSMALL / 4, 256, 0, stream>>>(cnt, srcs2, a2s, a2d, h2s, b2, val2);

  // fix rows 0..3
  k_tail<<<1, 256, 0, stream>>>(val2, vsm, decW, (float*)d_out);
}

// Round 14
// 56.954 us; speedup vs baseline: 1.3142x; 1.1414x over previous
//
#include <hip/hip_runtime.h>
#include <math.h>

// ---- problem constants (fixed by reference setup) ----
constexpr int Bc    = 4;
constexpr int Nc    = 1024;
constexpr int SEQc  = 512;
constexpr int FOURc = 257;              // rfft output length
constexpr int NROWS = Bc * Nc;          // 4096 (b,n) rows
constexpr int NSMALL = 1024;            // nodes touched by real edges
constexpr int F1c   = 30;               // H1*C1
constexpr int CAP   = 128;              // max in-degree bucket capacity
constexpr int XPAD  = 258;              // xf row stride (pad for 16B alignment)
constexpr float NEG_SLOPE = 0.2f;

#define DEVFN static __device__ __forceinline__

// ------- K_xf: double-folded Chebyshev cos-transform -> xf buffer -----------
// Fold 1: y[t] = x[t] + x[512-t], t=0..255 (y[0]=x[0]) + (-1)^k x[256].
// Fold 2: pair t <-> 256-t:  cos(k(256-t)a) = (-1)^k cos(kta), a = pi/256.
//   X[k] = y0 + sum_{t=1}^{127} (y[t] +/- y[256-t]) cos(kta)
//        + [k even] (-1)^(k/2) y128 + (-1)^k x256
// LDS holds zp/zm packed as float4; main loop = 127 x (1 ds_read_b128 + 6 FMA).
// Block = 256 thr = 4 waves = {2 rows x 2 col-halves}; lane owns k0, k0+1.
// Block 0 also zeroes bucket counters for k_pre (stream-ordered after us).
__global__ __launch_bounds__(256) void k_xf(
    const float* __restrict__ occ, const float* __restrict__ prc,
    float* __restrict__ xf, int* __restrict__ cnt) {
  __shared__ float4 z[2][128];            // [row][t]: zp_o, zp_p, zm_o, zm_p
  __shared__ float sp[2][6];              // y0_o,y0_p, y128_o,y128_p, x256_o,x256_p
  const int tid  = threadIdx.x;
  const int lane = tid & 63;
  const int wid  = tid >> 6;
  const int jrow = wid >> 1;              // local row 0..1
  const int half = wid & 1;               // column half 0..1
  const int row  = blockIdx.x * 2 + jrow;

  if (blockIdx.x == 0) {                  // zero bucket counters for k_pre
#pragma unroll
    for (int j = 0; j < 4; ++j) cnt[tid + 256 * j] = 0;
  }

  // staging: tid -> (row j = tid>>7, t = tid&127)
  {
    const int j = tid >> 7;
    const int t = tid & 127;
    const float* ro = occ + (size_t)(blockIdx.x * 2 + j) * SEQc;
    const float* rp = prc + (size_t)(blockIdx.x * 2 + j) * SEQc;
    if (t == 0) {
      sp[j][0] = ro[0];                 sp[j][1] = rp[0];
      sp[j][2] = ro[128] + ro[384];     sp[j][3] = rp[128] + rp[384];
      sp[j][4] = ro[256];               sp[j][5] = rp[256];
    } else {
      float ao = ro[t] + ro[SEQc - t];          // y[t]
      float bo = ro[256 - t] + ro[256 + t];     // y[256-t]
      float ap = rp[t] + rp[SEQc - t];
      float bp = rp[256 - t] + rp[256 + t];
      z[j][t] = make_float4(ao + bo, ap + bp, ao - bo, ap - bp);
    }
  }
  __syncthreads();

  // seeds for cols k0 (even), k0+1 (odd)
  const int k0 = half * 128 + 2 * lane;
  const float a = 6.283185307179586f / 512.0f;  // = pi/256
  float ce = cosf((float)k0 * a),       cpe = 1.f, m2e = 2.f * ce;
  float co = cosf((float)(k0 + 1) * a), cpo = 1.f, m2o = 2.f * co;
  float aeo = 0.f, aep = 0.f, aoo = 0.f, aop = 0.f;

#pragma unroll 4
  for (int t = 1; t < 128; ++t) {
    float4 zv = z[jrow][t];
    aeo = fmaf(zv.x, ce, aeo);
    aep = fmaf(zv.y, ce, aep);
    aoo = fmaf(zv.z, co, aoo);
    aop = fmaf(zv.w, co, aop);
    float ne = fmaf(m2e, ce, -cpe); cpe = ce; ce = ne;
    float no = fmaf(m2o, co, -cpo); cpo = co; co = no;
  }

  const float y0o = sp[jrow][0], y0p = sp[jrow][1];
  const float y128o = sp[jrow][2], y128p = sp[jrow][3];
  const float x256o = sp[jrow][4], x256p = sp[jrow][5];
  const float s128 = (lane & 1) ? -1.f : 1.f;   // (-1)^(k0/2), k0/2 = half*64+lane

  float4 st;                              // {Xe_o, Xe_p, Xo_o, Xo_p}
  st.x = aeo + y0o + s128 * y128o + x256o;
  st.y = aep + y0p + s128 * y128p + x256p;
  st.z = aoo + y0o - x256o;
  st.w = aop + y0p - x256p;
  *reinterpret_cast<float4*>(xf + ((size_t)row * XPAD + k0) * 2) = st;

  // k = 256 column: X256 = y0 + y128 + sum_{t=1}^{127} (-1)^t zp[t] + x256
  if (half == 0) {
    float sgn = (lane & 1) ? -1.f : 1.f;        // (-1)^lane = (-1)^(lane+64)
    float4 zhi = z[jrow][lane + 64];
    float so = sgn * zhi.x, spp = sgn * zhi.y;
    if (lane >= 1) {
      float4 zlo = z[jrow][lane];
      so  = fmaf(sgn, zlo.x, so);
      spp = fmaf(sgn, zlo.y, spp);
    }
#pragma unroll
    for (int off = 32; off; off >>= 1) {
      so  += __shfl_xor(so, off);
      spp += __shfl_xor(spp, off);
    }
    if (lane == 0) {
      float2 st2;
      st2.x = y0o + y128o + so + x256o;
      st2.y = y0p + y128p + spp + x256p;
      *reinterpret_cast<float2*>(xf + ((size_t)row * XPAD + 256) * 2) = st2;
    }
  }
}

// ------- K_pre: parallel bucket scatter (CSR-lite), 32 blocks -------
__global__ __launch_bounds__(256) void k_pre(const int* __restrict__ ei, int E,
                                             int* __restrict__ cnt,
                                             int* __restrict__ srcs2) {
  const int base = blockIdx.x * 256 + threadIdx.x;
  const int tot  = E + NSMALL;
  for (int e = base; e < tot; e += 32 * 256) {
    int src, dst;
    if (e < E) { src = ei[e]; dst = ei[E + e]; }
    else       { src = dst = e - E; }     // self loops
    int pos = atomicAdd(&cnt[dst], 1);
    if (pos < CAP) srcs2[dst * CAP + pos] = src;
  }
}

// self-loop-only node value: v = elu(xf@W1 + b1) @ W2 + b2
DEVFN float node_v(float xo, float xp,
                   const float* w1s, const float* b1s, const float* w2s, float b2v) {
  float s = 0.f;
#pragma unroll
  for (int jj = 0; jj < F1c; ++jj) {
    float h = fmaf(xo, w1s[jj], fmaf(xp, w1s[F1c + jj], b1s[jj]));
    float e = h > 0.f ? h : (__expf(h) - 1.f);
    s = fmaf(e, w2s[jj], s);
  }
  return s + b2v;
}

// layer-1 prep for small-graph nodes
DEVFN void small_prep(int node, float xo, float xp,
                      const float* w1s, const float* s1, const float* d1,
                      float* h1s, float* a1s, float* a1d) {
#pragma unroll
  for (int h = 0; h < 3; ++h) {
    float as = 0.f, ad = 0.f;
#pragma unroll
    for (int c = 0; c < 10; ++c) {
      int jj = h * 10 + c;
      float hv = fmaf(xo, w1s[jj], xp * w1s[F1c + jj]);
      h1s[node * F1c + jj] = hv;
      as = fmaf(hv, s1[jj], as);
      ad = fmaf(hv, d1[jj], ad);
    }
    a1s[node * 3 + h] = as;
    a1d[node * 3 + h] = ad;
  }
}

// ------- K_post: node_v + fused decode + small-graph prep ------------------
__global__ __launch_bounds__(256) void k_post(
    const float* __restrict__ xf,
    const float* __restrict__ W1, const float* __restrict__ b1,
    const float* __restrict__ W2, const float* __restrict__ b2,
    const float* __restrict__ as1, const float* __restrict__ ad1,
    const float* __restrict__ decW, const float* __restrict__ decb,
    float* __restrict__ out, float* __restrict__ vsm,
    float* __restrict__ h1s, float* __restrict__ a1s, float* __restrict__ a1d) {
  __shared__ float wl[192];               // W1(60) b1(30) W2(30) as1(30) ad1(30)
  __shared__ float red[4];
  const int tid = threadIdx.x;
  const int row = blockIdx.x;
  if      (tid < 60)  wl[tid] = W1[tid];
  else if (tid < 90)  wl[tid] = b1[tid - 60];
  else if (tid < 120) wl[tid] = W2[tid - 90];
  else if (tid < 150) wl[tid] = as1[tid - 120];
  else if (tid < 180) wl[tid] = ad1[tid - 150];
  __syncthreads();
  const float* w1s = wl;
  const float* b1s = wl + 60;
  const float* w2s = wl + 90;
  const float* s1  = wl + 120;
  const float* d1  = wl + 150;
  const float b2v  = b2[0];
  const bool smallrow = (row < 4);

  float2 v2 = *reinterpret_cast<const float2*>(xf + ((size_t)row * XPAD + tid) * 2);
  float vv = node_v(v2.x, v2.y, w1s, b1s, w2s, b2v);
  float s = vv * decW[tid];
  if (tid == 0) {                         // col 256
    float2 v6 = *reinterpret_cast<const float2*>(xf + ((size_t)row * XPAD + 256) * 2);
    float v256 = node_v(v6.x, v6.y, w1s, b1s, w2s, b2v);
    s = fmaf(v256, decW[256], s);
    if (smallrow) {
      int node = row * FOURc + 256;
      if (node < NSMALL) {
        vsm[node] = v256;
        small_prep(node, v6.x, v6.y, w1s, s1, d1, h1s, a1s, a1d);
      }
    }
  }
  if (smallrow) {
    int node = row * FOURc + tid;
    if (node < NSMALL) {
      vsm[node] = vv;
      small_prep(node, v2.x, v2.y, w1s, s1, d1, h1s, a1s, a1d);
    }
  }
#pragma unroll
  for (int off = 32; off; off >>= 1) s += __shfl_xor(s, off);
  if ((tid & 63) == 0) red[tid >> 6] = s;
  __syncthreads();
  if (tid == 0) out[row] = red[0] + red[1] + red[2] + red[3] + decb[0];
}

// ------- K_g1: layer-1 gather (one wave per dst) + layer-2 node prep -------
__global__ __launch_bounds__(256) void k_g1(
    const int* __restrict__ cnt, const int* __restrict__ srcs2,
    const float* __restrict__ a1s, const float* __restrict__ a1d,
    const float* __restrict__ h1s,
    const float* __restrict__ b1, const float* __restrict__ W2,
    const float* __restrict__ as2, const float* __restrict__ ad2,
    float* __restrict__ h2s, float* __restrict__ a2s, float* __restrict__ a2d) {
  const int lane = threadIdx.x & 63;
  const int dst  = blockIdx.x * 4 + (threadIdx.x >> 6);
  const int deg  = cnt[dst];
  const int* sp  = srcs2 + dst * CAP;
  const float ad0 = a1d[dst * 3], ad1v = a1d[dst * 3 + 1], ad2v = a1d[dst * 3 + 2];
  float den[3] = {0.f, 0.f, 0.f};
  float num[F1c];
#pragma unroll
  for (int j = 0; j < F1c; ++j) num[j] = 0.f;

  for (int p = lane; p < deg; p += 64) {
    int src = sp[p];
    const float* hs = h1s + src * F1c;
    float x0 = a1s[src * 3]     + ad0;
    float x1 = a1s[src * 3 + 1] + ad1v;
    float x2 = a1s[src * 3 + 2] + ad2v;
    x0 = x0 > 0.f ? x0 : NEG_SLOPE * x0;
    x1 = x1 > 0.f ? x1 : NEG_SLOPE * x1;
    x2 = x2 > 0.f ? x2 : NEG_SLOPE * x2;
    float e0 = __expf(x0), e1 = __expf(x1), e2 = __expf(x2);
    den[0] += e0; den[1] += e1; den[2] += e2;
#pragma unroll
    for (int c = 0; c < 10; ++c) {
      num[c]      = fmaf(e0, hs[c],      num[c]);
      num[10 + c] = fmaf(e1, hs[10 + c], num[10 + c]);
      num[20 + c] = fmaf(e2, hs[20 + c], num[20 + c]);
    }
  }
#pragma unroll
  for (int h = 0; h < 3; ++h)
#pragma unroll
    for (int off = 32; off; off >>= 1) den[h] += __shfl_xor(den[h], off);
#pragma unroll
  for (int j = 0; j < F1c; ++j)
#pragma unroll
    for (int off = 32; off; off >>= 1) num[j] += __shfl_xor(num[j], off);

  if (lane == 0) {
    float h2 = 0.f;
#pragma unroll
    for (int jj = 0; jj < F1c; ++jj) {
      float x2 = num[jj] / den[jj / 10] + b1[jj];
      x2 = x2 > 0.f ? x2 : (__expf(x2) - 1.f);
      h2 = fmaf(x2, W2[jj], h2);
    }
    h2s[dst] = h2;
    a2s[dst] = h2 * as2[0];
    a2d[dst] = h2 * ad2[0];
  }
}

// ------- K_g2: layer-2 gather (one wave per dst) -> final node value -------
__global__ __launch_bounds__(256) void k_g2(
    const int* __restrict__ cnt, const int* __restrict__ srcs2,
    const float* __restrict__ a2s, const float* __restrict__ a2d,
    const float* __restrict__ h2s, const float* __restrict__ b2,
    float* __restrict__ val2) {
  const int lane = threadIdx.x & 63;
  const int dst  = blockIdx.x * 4 + (threadIdx.x >> 6);
  const int deg  = cnt[dst];
  const int* sp  = srcs2 + dst * CAP;
  const float adv = a2d[dst];
  float den = 0.f, num = 0.f;
  for (int p = lane; p < deg; p += 64) {
    int src = sp[p];
    float x = a2s[src] + adv;
    x = x > 0.f ? x : NEG_SLOPE * x;
    float ex = __expf(x);
    den += ex;
    num = fmaf(ex, h2s[src], num);
  }
#pragma unroll
  for (int off = 32; off; off >>= 1) {
    den += __shfl_xor(den, off);
    num += __shfl_xor(num, off);
  }
  if (lane == 0) val2[dst] = num / den + b2[0];
}

// ------- K_tail: correct decode for rows 0..3 -------
__global__ __launch_bounds__(256) void k_tail(
    const float* __restrict__ val2, const float* __restrict__ vsm,
    const float* __restrict__ decW, float* __restrict__ out) {
  const int lane = threadIdx.x & 63;
  const int r    = threadIdx.x >> 6;      // rows 0..3
  float c = 0.f;
  for (int k = lane; k < FOURc; k += 64) {
    int node = r * FOURc + k;
    if (node < NSMALL) c += (val2[node] - vsm[node]) * decW[k];
  }
#pragma unroll
  for (int off = 32; off; off >>= 1) c += __shfl_xor(c, off);
  if (lane == 0) out[r] += c;
}

// ---------------- host launcher ----------------
extern "C" void kernel_launch(void* const* d_in, const int* in_sizes, int n_in,
                              void* d_out, int out_size, void* d_ws, size_t ws_size,
                              hipStream_t stream) {
  const float* occ  = (const float*)d_in[0];
  const float* prc  = (const float*)d_in[1];
  const int*   ei   = (const int*)d_in[2];
  const float* W1   = (const float*)d_in[3];
  const float* as1  = (const float*)d_in[4];
  const float* ad1  = (const float*)d_in[5];
  const float* b1   = (const float*)d_in[6];
  const float* W2   = (const float*)d_in[7];
  const float* as2  = (const float*)d_in[8];
  const float* ad2  = (const float*)d_in[9];
  const float* b2   = (const float*)d_in[10];
  const float* decW = (const float*)d_in[11];
  const float* decb = (const float*)d_in[12];
  const int E = in_sizes[2] / 2;

  float* ws = (float*)d_ws;
  float* xf   = ws;                       // NROWS * XPAD * 2
  float* h1s  = xf + (size_t)NROWS * XPAD * 2;  // 1024*30
  float* a1s  = h1s + NSMALL * F1c;       // 1024*3
  float* a1d  = a1s + NSMALL * 3;         // 1024*3
  float* h2s  = a1d + NSMALL * 3;         // 1024
  float* a2s  = h2s + NSMALL;             // 1024
  float* a2d  = a2s + NSMALL;             // 1024
  float* val2 = a2d + NSMALL;             // 1024
  float* vsm  = val2 + NSMALL;            // 1024
  int*   cnt  = (int*)(vsm + NSMALL);     // 1024
  int*   srcs2 = cnt + NSMALL;            // 1024*CAP

  // K_xf: double-folded recurrence transform (block 0 zeroes cnt)
  k_xf<<<NROWS / 2, 256, 0, stream>>>(occ, prc, xf, cnt);

  // K_pre: parallel bucket scatter (cnt zeroed by k_xf, stream-ordered)
  k_pre<<<32, 256, 0, stream>>>(ei, E, cnt, srcs2);

  // K_post: node_v + decode + small-graph prep (one block per row)
  k_post<<<NROWS, 256, 0, stream>>>(xf, W1, b1, W2, b2, as1, ad1,
                                    decW, decb, (float*)d_out, vsm,
                                    h1s, a1s, a1d);

  // small-graph gathers (no atomics)
  k_g1<<<NSMALL / 4, 256, 0, stream>>>(cnt, srcs2, a1s, a1d, h1s,
                                       b1, W2, as2, ad2, h2s, a2s, a2d);
  k_g2<<<NSMALL / 4, 256, 0, stream>>>(cnt, srcs2, a2s, a2d, h2s, b2, val2);

  // fix rows 0..3
  k_tail<<<1, 256, 0, stream>>>(val2, vsm, decW, (float*)d_out);
}